// Round 3
// baseline (242.574 us; speedup 1.0000x reference)
//
#include <hip/hip_runtime.h>
#include <hip/hip_bf16.h>

// ---------------------------------------------------------------------------
// Fused pipeline: [x @ Wqkv + b] -> GQA sliding-window attn (W=256, zero-pad
// softmax semantics, no 1/sqrt(d)) -> [attn @ Wo + bo]
// B=2 S=4096 DIM=1024 H=16 KV=2 D=64  -> rows = 8192
// Internal compute bf16 (fp32 accum). Tolerance is 2% of absmax -> safe.
// ---------------------------------------------------------------------------

typedef __attribute__((ext_vector_type(4))) float f32x4;
typedef __attribute__((ext_vector_type(8))) short s16x8;
typedef __attribute__((ext_vector_type(4))) short s16x4;

#define SEQ    4096
#define NROWS  8192
#define QKV_N  1280   // 1024 q | 128 k | 128 v

__device__ __forceinline__ unsigned short f2bf(float f) {
  union { float f; unsigned int u; } v; v.f = f;
  return (unsigned short)((v.u + 0x7FFFu + ((v.u >> 16) & 1u)) >> 16); // RNE
}

__device__ __forceinline__ void glds16(void* lds, const void* g) {
  void* gg = const_cast<void*>(g);
  __builtin_amdgcn_global_load_lds((__attribute__((address_space(1))) void*)gg,
                                   (__attribute__((address_space(3))) void*)lds,
                                   16, 0, 0);
}

__device__ __forceinline__ f32x4 mfma16(s16x8 a, s16x8 b, f32x4 c) {
  return __builtin_amdgcn_mfma_f32_16x16x32_bf16(a, b, c, 0, 0, 0);
}

// ---------------------------------------------------------------------------
// prep kernels
// ---------------------------------------------------------------------------
__global__ void convert_x(const float* __restrict__ x,
                          unsigned short* __restrict__ xb, int n) {
  int idx = (blockIdx.x * 256 + threadIdx.x) * 4;
  if (idx >= n) return;
  f32x4 v = *(const f32x4*)(x + idx);
  s16x4 o;
  o[0] = (short)f2bf(v[0]); o[1] = (short)f2bf(v[1]);
  o[2] = (short)f2bf(v[2]); o[3] = (short)f2bf(v[3]);
  *(s16x4*)(xb + idx) = o;
}

// Wt[n][k] = W*(k, n) for the concatenated [Wq|Wk|Wv] columns (N=1280, K=1024)
__global__ void transpose_qkv(const float* __restrict__ Wq,
                              const float* __restrict__ Wk,
                              const float* __restrict__ Wv,
                              unsigned short* __restrict__ Wt) {
  __shared__ float tile[32][33];
  int k0 = blockIdx.x * 32, n0 = blockIdx.y * 32;
  const float* src; int ld, cn0;
  if (n0 < 1024)      { src = Wq; ld = 1024; cn0 = n0; }
  else if (n0 < 1152) { src = Wk; ld = 128;  cn0 = n0 - 1024; }
  else                { src = Wv; ld = 128;  cn0 = n0 - 1152; }
  int tx = threadIdx.x, ty = threadIdx.y;
  #pragma unroll
  for (int r = 0; r < 32; r += 8)
    tile[ty + r][tx] = src[(k0 + ty + r) * ld + cn0 + tx];
  __syncthreads();
  #pragma unroll
  for (int r = 0; r < 32; r += 8)
    Wt[(n0 + ty + r) * 1024 + k0 + tx] = f2bf(tile[tx][ty + r]);
}

__global__ void transpose_wo(const float* __restrict__ W,
                             unsigned short* __restrict__ Wt) {
  __shared__ float tile[32][33];
  int k0 = blockIdx.x * 32, n0 = blockIdx.y * 32;
  int tx = threadIdx.x, ty = threadIdx.y;
  #pragma unroll
  for (int r = 0; r < 32; r += 8)
    tile[ty + r][tx] = W[(k0 + ty + r) * 1024 + n0 + tx];
  __syncthreads();
  #pragma unroll
  for (int r = 0; r < 32; r += 8)
    Wt[(n0 + ty + r) * 1024 + k0 + tx] = f2bf(tile[tx][ty + r]);
}

// ---------------------------------------------------------------------------
// m97-style 128x128 bf16 GEMM, B^T input, fused bias epilogue
// A[M][K] bf16, Bt[N][K] bf16, C[M][N] (bf16 or f32)
// ---------------------------------------------------------------------------
template<bool BIAS3, bool OUT_F32>
__global__ __launch_bounds__(256)
void gemm_bt(const unsigned short* __restrict__ A,
             const unsigned short* __restrict__ Bt,
             void* __restrict__ Cv,
             const float* __restrict__ b0,
             const float* __restrict__ b1,
             const float* __restrict__ b2,
             int M, int N, int K) {
  __shared__ unsigned short la[128 * 32];
  __shared__ unsigned short lb[128 * 32];
  const int tid = threadIdx.x;
  const int lane = tid & 63;
  const int wv = tid >> 6;
  const int wr = wv >> 1, wc = wv & 1;
  const int l15 = lane & 15, lch = lane >> 4;
  const int row0 = blockIdx.x * 128;
  const int col0 = blockIdx.y * 128;

  f32x4 acc[4][4] = {};

  const int cc0 = tid, cc1 = 256 + tid;
  const unsigned short* a0 = A + (row0 + (cc0 >> 2)) * K + (cc0 & 3) * 8;
  const unsigned short* a1 = A + (row0 + (cc1 >> 2)) * K + (cc1 & 3) * 8;
  const unsigned short* bp0 = Bt + (col0 + (cc0 >> 2)) * K + (cc0 & 3) * 8;
  const unsigned short* bp1 = Bt + (col0 + (cc1 >> 2)) * K + (cc1 & 3) * 8;
  unsigned short* la0 = &la[cc0 * 8];
  unsigned short* la1 = &la[cc1 * 8];
  unsigned short* lb0 = &lb[cc0 * 8];
  unsigned short* lb1 = &lb[cc1 * 8];

  for (int k0 = 0; k0 < K; k0 += 32) {
    __syncthreads();                 // previous tile fully consumed
    glds16(la0, a0 + k0);
    glds16(la1, a1 + k0);
    glds16(lb0, bp0 + k0);
    glds16(lb1, bp1 + k0);
    asm volatile("s_waitcnt vmcnt(0)" ::: "memory");
    __syncthreads();

    s16x8 af[4], bfr[4];
    #pragma unroll
    for (int mi = 0; mi < 4; ++mi)
      af[mi] = *(const s16x8*)&la[(wr * 64 + mi * 16 + l15) * 32 + lch * 8];
    #pragma unroll
    for (int ni = 0; ni < 4; ++ni)
      bfr[ni] = *(const s16x8*)&lb[(wc * 64 + ni * 16 + l15) * 32 + lch * 8];
    #pragma unroll
    for (int mi = 0; mi < 4; ++mi)
      #pragma unroll
      for (int ni = 0; ni < 4; ++ni)
        acc[mi][ni] = mfma16(af[mi], bfr[ni], acc[mi][ni]);
  }

  #pragma unroll
  for (int mi = 0; mi < 4; ++mi) {
    #pragma unroll
    for (int ni = 0; ni < 4; ++ni) {
      int c = col0 + wc * 64 + ni * 16 + l15;
      float bias;
      if constexpr (BIAS3)
        bias = (c < 1024) ? b0[c] : (c < 1152) ? b1[c - 1024] : b2[c - 1152];
      else
        bias = b0[c];
      #pragma unroll
      for (int j = 0; j < 4; ++j) {
        int r = row0 + wr * 64 + mi * 16 + lch * 4 + j;
        float v = acc[mi][ni][j] + bias;
        if constexpr (OUT_F32) ((float*)Cv)[(long)r * N + c] = v;
        else ((unsigned short*)Cv)[(long)r * N + c] = f2bf(v);
      }
    }
  }
}

// ---------------------------------------------------------------------------
// sliding-window GQA attention
// block = (b, h, 64-query tile); 4 waves x 16 queries; key span = 320
// zero-pad semantics: in-window out-of-range keys get raw score 0 (counted in
// softmax denominator), and contribute 0 to PV (V rows staged as zeros).
// ---------------------------------------------------------------------------
#define SPAN 320
#define VSTR 328   // Vt / P row stride (bf16 elems); 2-way banks, 16B aligned

__global__ __launch_bounds__(256)
void attn_win(const unsigned short* __restrict__ qkv,
              unsigned short* __restrict__ aout) {
  __shared__ unsigned short Kl[SPAN * 64];       // XOR-swizzled rows
  __shared__ unsigned short Vt[64 * VSTR];       // V transposed: [d][key]
  __shared__ unsigned short Pl[4 * 16 * VSTR];   // per-wave P rows

  const int tid = threadIdx.x;
  const int lane = tid & 63;
  const int w = tid >> 6;
  const int l15 = lane & 15, lch = lane >> 4;
  const int qt = blockIdx.x, h = blockIdx.y, b = blockIdx.z;
  const int kvh = h >> 3;                         // H/KV = 8
  const int qbase = qt * 64;
  const int kstart = qbase - 128;                 // may be negative
  const int rowbase = b * SEQ;

  // Q fragments straight from global (tiny, L2-served, reused 20x)
  s16x8 qa0, qa1;
  {
    const unsigned short* src =
        qkv + (rowbase + qbase + w * 16 + l15) * QKV_N + h * 64 + lch * 8;
    qa0 = *(const s16x8*)src;
    qa1 = *(const s16x8*)(src + 32);
  }

  // stage K (swizzled row-major) + V (transposed); zero rows outside [0,S)
  #pragma unroll
  for (int i = 0; i < 10; ++i) {
    int cc = i * 256 + tid;            // 8-elem chunk id
    int row = cc >> 3;                 // 0..319
    int col = (cc & 7) * 8;            // 0..56
    int key = kstart + row;
    s16x8 vk = {0, 0, 0, 0, 0, 0, 0, 0};
    s16x8 vv = {0, 0, 0, 0, 0, 0, 0, 0};
    if (key >= 0 && key < SEQ) {
      const unsigned short* base = qkv + (rowbase + key) * QKV_N;
      vk = *(const s16x8*)(base + 1024 + kvh * 64 + col);
      vv = *(const s16x8*)(base + 1152 + kvh * 64 + col);
    }
    int kb = (row * 128 + col * 2) ^ ((row & 7) << 4);
    *(s16x8*)((char*)Kl + kb) = vk;
    #pragma unroll
    for (int j = 0; j < 8; ++j)
      Vt[(col + j) * VSTR + row] = (unsigned short)vv[j];
  }
  __syncthreads();

  // QK^T : 20 key tiles x (K=64 over 2 mfma steps)
  f32x4 sc[20];
  #pragma unroll
  for (int kt = 0; kt < 20; ++kt) {
    int key = kt * 16 + l15;
    int swz = (key & 7) << 4;
    s16x8 k0 = *(const s16x8*)((char*)Kl + ((key * 128 + lch * 16) ^ swz));
    s16x8 k1 = *(const s16x8*)((char*)Kl + ((key * 128 + 64 + lch * 16) ^ swz));
    f32x4 a = {0.f, 0.f, 0.f, 0.f};
    a = mfma16(qa0, k0, a);
    a = mfma16(qa1, k1, a);
    sc[kt] = a;
  }

  // mask: out-of-window -> -inf ; in-window out-of-range -> raw 0 (pad)
  #pragma unroll
  for (int kt = 0; kt < 20; ++kt) {
    int u = kt * 16 + l15;
    int kpos = kstart + u;
    bool inr = (kpos >= 0) && (kpos < SEQ);
    #pragma unroll
    for (int j = 0; j < 4; ++j) {
      int tq = w * 16 + lch * 4 + j;   // query's span index
      float v = sc[kt][j];
      v = (u >= tq && u < tq + 256) ? (inr ? v : 0.0f) : -3.0e38f;
      sc[kt][j] = v;
    }
  }

  // wave-parallel row softmax (16-lane group shuffle reduce)
  float inv[4];
  #pragma unroll
  for (int j = 0; j < 4; ++j) {
    float mx = sc[0][j];
    #pragma unroll
    for (int kt = 1; kt < 20; ++kt) mx = fmaxf(mx, sc[kt][j]);
    mx = fmaxf(mx, __shfl_xor(mx, 1, 64));
    mx = fmaxf(mx, __shfl_xor(mx, 2, 64));
    mx = fmaxf(mx, __shfl_xor(mx, 4, 64));
    mx = fmaxf(mx, __shfl_xor(mx, 8, 64));
    float sm = 0.f;
    #pragma unroll
    for (int kt = 0; kt < 20; ++kt) {
      float p = __expf(sc[kt][j] - mx);
      sc[kt][j] = p;
      sm += p;
    }
    sm += __shfl_xor(sm, 1, 64);
    sm += __shfl_xor(sm, 2, 64);
    sm += __shfl_xor(sm, 4, 64);
    sm += __shfl_xor(sm, 8, 64);
    inv[j] = 1.0f / sm;
  }

  // write normalized P (bf16); zero P at pad keys (V=0 semantics)
  unsigned short* Pw = Pl + w * 16 * VSTR;
  #pragma unroll
  for (int kt = 0; kt < 20; ++kt) {
    int u = kt * 16 + l15;
    int kpos = kstart + u;
    bool inr = (kpos >= 0) && (kpos < SEQ);
    #pragma unroll
    for (int j = 0; j < 4; ++j) {
      float p = inr ? sc[kt][j] * inv[j] : 0.0f;
      Pw[(lch * 4 + j) * VSTR + u] = f2bf(p);
    }
  }
  __syncthreads();

  // PV: O[16][64] += P[16][320] * V[320][64]
  f32x4 oa[4] = {};
  #pragma unroll
  for (int ks = 0; ks < 10; ++ks) {
    s16x8 pa = *(const s16x8*)&Pw[l15 * VSTR + ks * 32 + lch * 8];
    #pragma unroll
    for (int nt = 0; nt < 4; ++nt) {
      s16x8 bvf = *(const s16x8*)&Vt[(nt * 16 + l15) * VSTR + ks * 32 + lch * 8];
      oa[nt] = mfma16(pa, bvf, oa[nt]);
    }
  }

  #pragma unroll
  for (int nt = 0; nt < 4; ++nt)
    #pragma unroll
    for (int j = 0; j < 4; ++j) {
      int r = rowbase + qbase + w * 16 + lch * 4 + j;
      aout[(long)r * 1024 + h * 64 + nt * 16 + l15] = f2bf(oa[nt][j]);
    }
}

// ---------------------------------------------------------------------------
extern "C" void kernel_launch(void* const* d_in, const int* in_sizes, int n_in,
                              void* d_out, int out_size, void* d_ws, size_t ws_size,
                              hipStream_t stream) {
  const float* x  = (const float*)d_in[0];
  const float* Wq = (const float*)d_in[1];
  const float* bq = (const float*)d_in[2];
  const float* Wk = (const float*)d_in[3];
  const float* bk = (const float*)d_in[4];
  const float* Wv = (const float*)d_in[5];
  const float* bv = (const float*)d_in[6];
  const float* Wo = (const float*)d_in[7];
  const float* bo = (const float*)d_in[8];
  float* out = (float*)d_out;

  // workspace layout (bytes): total ~42.5 MB
  // attno aliases xb: xb is dead after the QKV GEMM completes (same stream).
  char* ws = (char*)d_ws;
  unsigned short* xb    = (unsigned short*)(ws);                     // 16,777,216
  unsigned short* attno = (unsigned short*)(ws);                     // alias of xb
  unsigned short* wqkvt = (unsigned short*)(ws + 16777216);          //  2,621,440
  unsigned short* wot   = (unsigned short*)(ws + 19398656);          //  2,097,152
  unsigned short* qkv   = (unsigned short*)(ws + 21495808);          // 20,971,520

  convert_x<<<8192, 256, 0, stream>>>(x, xb, NROWS * 1024);
  transpose_qkv<<<dim3(32, 40), dim3(32, 8), 0, stream>>>(Wq, Wk, Wv, wqkvt);
  transpose_wo<<<dim3(32, 32), dim3(32, 8), 0, stream>>>(Wo, wot);

  gemm_bt<true, false><<<dim3(NROWS / 128, QKV_N / 128), 256, 0, stream>>>(
      xb, wqkvt, (void*)qkv, bq, bk, bv, NROWS, QKV_N, 1024);

  attn_win<<<dim3(64, 16, 2), 256, 0, stream>>>(qkv, attno);

  gemm_bt<false, true><<<dim3(NROWS / 128, 1024 / 128), 256, 0, stream>>>(
      attno, wot, (void*)out, bo, nullptr, nullptr, NROWS, 1024, 1024);
}